// Round 7
// baseline (131.321 us; speedup 1.0000x reference)
//
#include <hip/hip_runtime.h>
#include <hip/hip_bf16.h>
#include <stdint.h>

#define T_STEPS 8192
#define NN 64
#define FF 128
#define HH 128
#define OO 128
#define TPB_T 8

typedef _Float16 f16;
typedef __attribute__((ext_vector_type(8))) _Float16 f16x8;
typedef __attribute__((ext_vector_type(4))) _Float16 f16x4;
typedef __attribute__((ext_vector_type(4))) float f32x4;

// ---------------- prep: norm (f16) + bc = b_enc @ W_gcn (f32) ----------------
__global__ void prep_norm_kernel(const int* __restrict__ src, const int* __restrict__ dst, int E,
                                 const float* __restrict__ benc, const float* __restrict__ wgcn,
                                 f16* __restrict__ normg, float* __restrict__ bcg)
{
    __shared__ float A[NN * NN];
    __shared__ float din[NN], dout[NN];
    const int tid = threadIdx.x;
    for (int i = tid; i < NN * NN; i += 256) A[i] = 0.0f;
    __syncthreads();
    for (int e = tid; e < E; e += 256) atomicAdd(&A[dst[e] * NN + src[e]], 1.0f);
    __syncthreads();
    if (tid < NN) A[tid * NN + tid] += 1.0f;
    __syncthreads();
    if (tid < NN) {               // deg_in[i] = row sum
        float s = 0.f;
        for (int j = 0; j < NN; ++j) s += A[tid * NN + j];
        din[tid] = s;
    } else if (tid < 2 * NN) {    // deg_out[j] = col sum
        int j = tid - NN;
        float s = 0.f;
        for (int i = 0; i < NN; ++i) s += A[i * NN + j];
        dout[j] = s;
    }
    __syncthreads();
    if (tid < NN) {
        float ri = rsqrtf(din[tid]);
        for (int j = 0; j < NN; ++j)
            normg[tid * NN + j] = (f16)(A[tid * NN + j] * ri * rsqrtf(dout[j]));
    }
    if (tid >= 128) {             // bc[o] = b_enc @ W_gcn
        int o = tid - 128;
        float s = 0.f;
        for (int h = 0; h < HH; ++h) s += benc[h] * wgcn[h * OO + o];
        bcg[o] = s;
    }
}

// ---------------- prep: WcT[o][f] = (W_enc @ W_gcn)^T (f16) ----------------
__global__ void prep_wc_kernel(const float* __restrict__ wenc, const float* __restrict__ wgcn,
                               f16* __restrict__ wctg)
{
    int o = blockIdx.x * 2 + (threadIdx.x >> 7);
    int f = threadIdx.x & 127;
    float s = 0.f;
    for (int h = 0; h < HH; ++h) s += wenc[f * HH + h] * wgcn[h * OO + o];
    wctg[o * FF + f] = (f16)s;
}

// async global->LDS, 16B per lane; LDS dest = wave-uniform base + lane*16 (HW rule, m104)
__device__ __forceinline__ void dma16(const float* g, float* l) {
    __builtin_amdgcn_global_load_lds(
        (const __attribute__((address_space(1))) uint32_t*)g,
        (__attribute__((address_space(3))) uint32_t*)l, 16, 0, 0);
}

// ---------------- fused main: out[t] = norm @ (x[t] @ Wc + 1*bc) + 1*bgcn ----------------
__global__ __launch_bounds__(256, 2) void fused_kernel(
    const float* __restrict__ x, const f16* __restrict__ normg,
    const f16* __restrict__ wctg, const float* __restrict__ bcg,
    const float* __restrict__ bgcn, float* __restrict__ out)
{
    // 2 x-buffers (f32, LINEAR [64][128] as required by global_load_lds; data
    // pre-permuted via the global SOURCE address: buffer[row][f] = x[row][f ^ ((row&7)<<2)])
    __shared__ float xb0[NN * FF];     // 32768 B
    __shared__ float xb1[NN * FF];     // 32768 B
    __shared__ f16 h2t[OO * NN];       // 16384 B, XOR-swizzled  -> total exactly 80 KB, 2 blocks/CU

    const int tid = threadIdx.x;
    const int lane = tid & 63;
    const int w = tid >> 6;        // wave 0..3 -> output cols w*32..w*32+31
    const int l15 = lane & 15;
    const int lg = lane >> 4;      // 0..3

    // persistent register frags
    f16x8 wcf[2][4];               // Wc B-frags for this wave's col slice
#pragma unroll
    for (int ct = 0; ct < 2; ++ct)
#pragma unroll
        for (int kk = 0; kk < 4; ++kk)
            wcf[ct][kk] = *(const f16x8*)(wctg + (w * 32 + ct * 16 + l15) * FF + kk * 32 + lg * 8);

    f16x8 nf[4][2];                // norm frags (B-operand of swapped matmul2)
#pragma unroll
    for (int rt = 0; rt < 4; ++rt)
#pragma unroll
        for (int kk = 0; kk < 2; ++kk)
            nf[rt][kk] = *(const f16x8*)(normg + (rt * 16 + l15) * NN + kk * 32 + lg * 8);

    f32x4 bcs[2];                  // bc splat (acc1 init)
#pragma unroll
    for (int ct = 0; ct < 2; ++ct) {
        float v = bcg[w * 32 + ct * 16 + l15];
        bcs[ct][0] = v; bcs[ct][1] = v; bcs[ct][2] = v; bcs[ct][3] = v;
    }
    f32x4 bgf[2];                  // bgcn frag (acc2 init)
#pragma unroll
    for (int ct = 0; ct < 2; ++ct)
        bgf[ct] = *(const f32x4*)(bgcn + w * 32 + ct * 16 + lg * 4);

    const int t0 = blockIdx.x * TPB_T;

    // stage one t-step: 8 DMA instrs/thread; chunk c = 1KB = 2 rows.
    // source slot pre-swizzled so reads can XOR-deswizzle (rule #21 both-sides pattern)
    auto stage_x = [&](const float* xt, float* dst) {
#pragma unroll
        for (int j = 0; j < 8; ++j) {
            int c = w * 8 + j;                     // 0..31
            int row = c * 2 + (lane >> 5);         // 0..63
            int slot = (lane & 31) ^ (row & 7);    // 16B slot within the 512B row
            dma16(xt + row * FF + slot * 4, dst + c * 256);
        }
    };

    auto compute = [&](const float* cur, int t) {
        // S4: matmul1  h2' = x_t @ Wc + 1*bc
        f32x4 acc1[4][2];
#pragma unroll
        for (int rt = 0; rt < 4; ++rt)
#pragma unroll
            for (int ct = 0; ct < 2; ++ct)
                acc1[rt][ct] = bcs[ct];
#pragma unroll
        for (int kk = 0; kk < 4; ++kk) {
            f16x8 af[4];
#pragma unroll
            for (int rt = 0; rt < 4; ++rt) {
                int row = rt * 16 + l15;
                int sw = (row & 7) << 2;           // dword-XOR = 16B-slot XOR
                int d0 = kk * 32 + lg * 8;
                f32x4 a0 = *(const f32x4*)(cur + row * FF + (d0 ^ sw));
                f32x4 a1 = *(const f32x4*)(cur + row * FF + ((d0 + 4) ^ sw));
                f16x8 v;
                v[0] = (f16)a0[0]; v[1] = (f16)a0[1]; v[2] = (f16)a0[2]; v[3] = (f16)a0[3];
                v[4] = (f16)a1[0]; v[5] = (f16)a1[1]; v[6] = (f16)a1[2]; v[7] = (f16)a1[3];
                af[rt] = v;
            }
#pragma unroll
            for (int rt = 0; rt < 4; ++rt)
#pragma unroll
                for (int ct = 0; ct < 2; ++ct)
                    acc1[rt][ct] = __builtin_amdgcn_mfma_f32_16x16x32_f16(
                        af[rt], wcf[ct][kk], acc1[rt][ct], 0, 0, 0);
        }

        // S5: wave-private transpose into swizzled h2t (no barrier; same-wave lgkm ordering)
#pragma unroll
        for (int rt = 0; rt < 4; ++rt)
#pragma unroll
            for (int ct = 0; ct < 2; ++ct) {
                f16x4 hv;
#pragma unroll
                for (int r = 0; r < 4; ++r) hv[r] = (f16)acc1[rt][ct][r];
                int col = w * 32 + ct * 16 + l15;
                int idx = (col * 64 + rt * 16 + lg * 4) ^ ((col & 7) << 3);
                *(f16x4*)(h2t + idx) = hv;
            }

        // S7: matmul2 swapped: D = h2'^T * norm^T (lane -> 4 consecutive out cols)
        f32x4 acc2[2][4];
#pragma unroll
        for (int ct = 0; ct < 2; ++ct)
#pragma unroll
            for (int rt = 0; rt < 4; ++rt)
                acc2[ct][rt] = bgf[ct];
#pragma unroll
        for (int kk = 0; kk < 2; ++kk) {
            f16x8 bf[2];
#pragma unroll
            for (int ct = 0; ct < 2; ++ct) {
                int col = w * 32 + ct * 16 + l15;
                int idx = (col * 64 + kk * 32 + lg * 8) ^ ((col & 7) << 3);
                bf[ct] = *(const f16x8*)(h2t + idx);
            }
#pragma unroll
            for (int ct = 0; ct < 2; ++ct)
#pragma unroll
                for (int rt = 0; rt < 4; ++rt)
                    acc2[ct][rt] = __builtin_amdgcn_mfma_f32_16x16x32_f16(
                        bf[ct], nf[rt][kk], acc2[ct][rt], 0, 0, 0);
        }

        // epilogue: float4 stores (full 128B lines); never drained in-loop
        float* op = out + (size_t)t * (NN * OO);
#pragma unroll
        for (int rt = 0; rt < 4; ++rt)
#pragma unroll
            for (int ct = 0; ct < 2; ++ct)
                *(f32x4*)(op + (rt * 16 + l15) * OO + w * 32 + ct * 16 + lg * 4) = acc2[ct][rt];
    };

    // prologue: stage t0, full drain once, barrier
    stage_x(x + (size_t)t0 * (NN * FF), xb0);
    __builtin_amdgcn_sched_barrier(0);
    asm volatile("s_waitcnt vmcnt(0)");
    __builtin_amdgcn_sched_barrier(0);
    __builtin_amdgcn_s_barrier();
    __builtin_amdgcn_sched_barrier(0);

#pragma unroll 1
    for (int i = 0; i < TPB_T; i += 2) {
        // ---- iter A: consume xb0, stage xb1 for t0+i+1 ----
        stage_x(x + (size_t)(t0 + i + 1) * (NN * FF), xb1);   // i+1 <= 7 always valid
        __builtin_amdgcn_sched_barrier(0);
        compute(xb0, t0 + i);
        __builtin_amdgcn_sched_barrier(0);
        // counted wait: drains this iter's 8 DMAs, leaves the 8 stores in flight
        asm volatile("s_waitcnt vmcnt(8)");
        __builtin_amdgcn_sched_barrier(0);
        __builtin_amdgcn_s_barrier();
        __builtin_amdgcn_sched_barrier(0);

        // ---- iter B: consume xb1, stage xb0 for t0+i+2 ----
        if (i + 2 < TPB_T) stage_x(x + (size_t)(t0 + i + 2) * (NN * FF), xb0);
        __builtin_amdgcn_sched_barrier(0);
        compute(xb1, t0 + i + 1);
        if (i + 2 < TPB_T) {
            __builtin_amdgcn_sched_barrier(0);
            asm volatile("s_waitcnt vmcnt(8)");
            __builtin_amdgcn_sched_barrier(0);
            __builtin_amdgcn_s_barrier();
            __builtin_amdgcn_sched_barrier(0);
        }
    }
}

extern "C" void kernel_launch(void* const* d_in, const int* in_sizes, int n_in,
                              void* d_out, int out_size, void* d_ws, size_t ws_size,
                              hipStream_t stream)
{
    const float* x    = (const float*)d_in[0];
    const float* wenc = (const float*)d_in[1];
    const float* benc = (const float*)d_in[2];
    const float* wgcn = (const float*)d_in[3];
    const float* bgcn = (const float*)d_in[4];
    const int*   src  = (const int*)d_in[5];
    const int*   dst  = (const int*)d_in[6];
    const int E = in_sizes[5];

    // workspace: WcT f16 [128*128] (32768 B) | norm f16 [64*64] (8192 B) | bc f32 [128] (512 B)
    f16*   wctg  = (f16*)d_ws;
    f16*   normg = (f16*)((char*)d_ws + 32768);
    float* bcg   = (float*)((char*)d_ws + 32768 + 8192);

    prep_norm_kernel<<<1, 256, 0, stream>>>(src, dst, E, benc, wgcn, normg, bcg);
    prep_wc_kernel<<<OO / 2, 256, 0, stream>>>(wenc, wgcn, wctg);
    fused_kernel<<<T_STEPS / TPB_T, 256, 0, stream>>>(x, normg, wctg, bcg, bgcn, (float*)d_out);
}